// Round 7
// baseline (583.892 us; speedup 1.0000x reference)
//
#include <hip/hip_runtime.h>

#define FDIM 128  // feature dim == hidden dim

typedef __attribute__((ext_vector_type(8))) short short8;   // 8 bf16 (4 VGPRs)
typedef __attribute__((ext_vector_type(4))) float f32x4;    // MFMA accumulator

__device__ inline unsigned short f2bf(float f) {  // round-to-nearest-even
    unsigned int u = __float_as_uint(f);
    unsigned int r = u + 0x7FFFu + ((u >> 16) & 1u);
    return (unsigned short)(r >> 16);
}
__device__ inline float bf2f(unsigned short b) {
    return __uint_as_float((unsigned int)b << 16);
}
__device__ inline void bf8_fma(short8 v, float c, float* acc) {
#pragma unroll
    for (int k = 0; k < 8; ++k)
        acc[k] = fmaf(bf2f(((const unsigned short*)&v)[k]), c, acc[k]);
}

// ---------------------------------------------------------------------------
// 1) heterogeneous pre-pass: blocks [0,statBlocks) = column sum/sumsq partials
//    (BW-bound sweep of x); blocks >= statBlocks = dst-degree atomics
//    (latency-bound) — merged so the two run concurrently.
__global__ __launch_bounds__(256) void pre_combo(const float* __restrict__ x, int N,
                                                 float* __restrict__ partials, int statBlocks,
                                                 const int* __restrict__ dst, int E,
                                                 int* __restrict__ cnt) {
    if ((int)blockIdx.x >= statBlocks) {
        int e = (blockIdx.x - statBlocks) * 256 + threadIdx.x;
        if (e < E) atomicAdd(&cnt[dst[e]], 1);
        return;
    }
    const int c4 = threadIdx.x & 31;
    const int rg = threadIdx.x >> 5;
    float4 s = make_float4(0.f, 0.f, 0.f, 0.f);
    float4 q = make_float4(0.f, 0.f, 0.f, 0.f);
    for (long r = (long)blockIdx.x * 8 + rg; r < N; r += (long)statBlocks * 8) {
        float4 v = ((const float4*)x)[r * 32 + c4];
        s.x += v.x; s.y += v.y; s.z += v.z; s.w += v.w;
        q.x += v.x * v.x; q.y += v.y * v.y; q.z += v.z * v.z; q.w += v.w * v.w;
    }
    __shared__ float red[8][32][8];
    float* p = red[rg][c4];
    p[0] = s.x; p[1] = s.y; p[2] = s.z; p[3] = s.w;
    p[4] = q.x; p[5] = q.y; p[6] = q.z; p[7] = q.w;
    __syncthreads();
    if (rg == 0) {
#pragma unroll
        for (int g = 1; g < 8; ++g) {
            const float* o = red[g][c4];
#pragma unroll
            for (int j = 0; j < 8; ++j) red[0][c4][j] += o[j];
        }
        const float* r0 = red[0][c4];
        float* out = &partials[(size_t)blockIdx.x * 256];
        ((float4*)out)[c4] = make_float4(r0[0], r0[1], r0[2], r0[3]);
        ((float4*)(out + 128))[c4] = make_float4(r0[4], r0[5], r0[6], r0[7]);
    }
}

// ---------------------------------------------------------------------------
// 2) fused stats-reduce + weight transpose. 16 blocks; each block redundantly
//    reduces the partials (L2-hit, ~0.5 MB) into mean/rstd in LDS, then does
//    its 16-row j-slice of the transpose. Blocks 0-7: W1 (scaled, bias0
//    partials via atomics into zeroed bias0). Blocks 8-15: W2.
__global__ __launch_bounds__(256) void stats_prep(const float* __restrict__ partials,
                                                  int nblk, int N,
                                                  const float* __restrict__ W1,
                                                  const float* __restrict__ W2,
                                                  unsigned short* __restrict__ WT1,
                                                  unsigned short* __restrict__ WT2,
                                                  float* __restrict__ bias0) {
    __shared__ float mean_sh[FDIM], rstd_sh[FDIM];
    __shared__ float red[2][2][FDIM];
    const int half = threadIdx.x >> 7;  // 0,1
    const int j = threadIdx.x & 127;
    float s = 0.f, q = 0.f;
    for (int b = half; b < nblk; b += 2) {
        s += partials[(size_t)b * 256 + j];
        q += partials[(size_t)b * 256 + 128 + j];
    }
    red[half][0][j] = s;
    red[half][1][j] = q;
    __syncthreads();
    if (half == 0) {
        s += red[1][0][j];
        q += red[1][1][j];
        float m = s / (float)N;
        float var = (q - (float)N * m * m) / (float)(N - 1);
        mean_sh[j] = m;
        rstd_sh[j] = rsqrtf(var);
    }
    __syncthreads();

    const int b = blockIdx.x;
    const int h = j;                       // output row of WT
    const int jbase0 = (threadIdx.x >> 7) * 8;  // which 8 of the block's 16 j's
    if (b < 8) {
        float acc = 0.f;
#pragma unroll
        for (int jj = 0; jj < 8; ++jj) {
            int j2 = b * 16 + jbase0 + jj;
            float w = W1[j2 * FDIM + h] * rstd_sh[j2];
            WT1[h * FDIM + j2] = f2bf(w);
            acc += mean_sh[j2] * w;
        }
        unsafeAtomicAdd(&bias0[h], -acc);
    } else {
#pragma unroll
        for (int jj = 0; jj < 8; ++jj) {
            int j2 = (b - 8) * 16 + jbase0 + jj;
            WT2[h * FDIM + j2] = f2bf(W2[j2 * FDIM + h]);
        }
    }
}

// ---------------------------------------------------------------------------
// 3) contiguous per-node edge ranges + dinv (fused)
__global__ __launch_bounds__(256) void alloc_offsets(const int* __restrict__ cnt, int N,
                                                     int* __restrict__ start,
                                                     int* __restrict__ wcur,
                                                     int* __restrict__ counter,
                                                     float* __restrict__ dinv) {
    __shared__ int sh[256];
    __shared__ int base;
    int i = blockIdx.x * 256 + threadIdx.x;
    int v = (i < N) ? cnt[i] : 0;
    sh[threadIdx.x] = v;
    __syncthreads();
    for (int off = 1; off < 256; off <<= 1) {
        int t = (threadIdx.x >= off) ? sh[threadIdx.x - off] : 0;
        __syncthreads();
        sh[threadIdx.x] += t;
        __syncthreads();
    }
    if (threadIdx.x == 255) base = atomicAdd(counter, sh[255]);
    __syncthreads();
    int excl = base + sh[threadIdx.x] - v;
    if (i < N) {
        start[i] = excl;
        wcur[i] = excl;
        dinv[i] = rsqrtf((float)v + 1.0f);
    }
}

// 4) bucket edges by dst; one 8B store per edge: {src, coef bits}
__global__ void fill_edges(const int* __restrict__ src, const int* __restrict__ dst,
                           const float* __restrict__ dinv, int E,
                           int* __restrict__ wcur, int2* __restrict__ edata) {
    int e = blockIdx.x * blockDim.x + threadIdx.x;
    if (e >= E) return;
    int s = src[e], d = dst[e];
    int pos = atomicAdd(&wcur[d], 1);
    edata[pos] = make_int2(s, __float_as_int(dinv[s] * dinv[d]));
}

// ---------------------------------------------------------------------------
// 5) bf16 MFMA GEMM: C_bf16[M x 128] = A[M x 128] @ W[128 x 128] (+ bias)
template <typename T>
__global__ __launch_bounds__(256) void gemm_mfma(const T* __restrict__ A,
                                                 const unsigned short* __restrict__ WT,
                                                 const float* __restrict__ bias,
                                                 unsigned short* __restrict__ C, int M) {
    constexpr int LDA = 136;
    __shared__ unsigned short Alds[64 * LDA];
    __shared__ unsigned short Wlds[FDIM * LDA];
    const int tid = threadIdx.x;
    const int row0 = blockIdx.x * 64;

    for (int i = tid; i < FDIM * 16; i += 256) {
        int r = i >> 4, g = i & 15;
        *(int4*)&Wlds[r * LDA + g * 8] = *(const int4*)&WT[r * FDIM + g * 8];
    }
    if constexpr (sizeof(T) == 4) {
        for (int i = tid; i < 64 * 32; i += 256) {
            int r = i >> 5, c4 = i & 31;
            int row = row0 + r;
            float4 v = make_float4(0.f, 0.f, 0.f, 0.f);
            if (row < M) v = ((const float4*)A)[(size_t)row * 32 + c4];
            ushort4 p;
            p.x = f2bf(v.x); p.y = f2bf(v.y); p.z = f2bf(v.z); p.w = f2bf(v.w);
            *(ushort4*)&Alds[r * LDA + c4 * 4] = p;
        }
    } else {
        for (int i = tid; i < 64 * 16; i += 256) {
            int r = i >> 4, g = i & 15;
            int row = row0 + r;
            int4 v = make_int4(0, 0, 0, 0);
            if (row < M) v = *(const int4*)&A[(size_t)row * FDIM + g * 8];
            *(int4*)&Alds[r * LDA + g * 8] = v;
        }
    }
    __syncthreads();

    const int lane = tid & 63;
    const int wave = tid >> 6;
    const int m16 = lane & 15;
    const int quad = lane >> 4;

    f32x4 acc[8];
#pragma unroll
    for (int t = 0; t < 8; ++t) acc[t] = (f32x4){0.f, 0.f, 0.f, 0.f};

    const unsigned short* Abase = &Alds[(wave * 16 + m16) * LDA + quad * 8];
    const unsigned short* Wbase = &Wlds[m16 * LDA + quad * 8];
#pragma unroll
    for (int s = 0; s < 4; ++s) {
        short8 a = *(const short8*)&Abase[s * 32];
#pragma unroll
        for (int t = 0; t < 8; ++t) {
            short8 b = *(const short8*)&Wbase[t * 16 * LDA + s * 32];
            acc[t] = __builtin_amdgcn_mfma_f32_16x16x32_bf16(a, b, acc[t], 0, 0, 0);
        }
    }

#pragma unroll
    for (int t = 0; t < 8; ++t) {
        float bv = bias ? bias[t * 16 + m16] : 0.f;
#pragma unroll
        for (int i = 0; i < 4; ++i) {
            int r = row0 + wave * 16 + quad * 4 + i;
            if (r < M) C[(size_t)r * FDIM + t * 16 + m16] = f2bf(acc[t][i] + bv);
        }
    }
}

// ---------------------------------------------------------------------------
// 6) aggregation (bf16 in, fp32 accum, relu). 16 lanes/node, 16 nodes/block,
//    4x-unrolled edge loop. POOL=false: store bf16 rows. POOL=true: pool
//    directly into d_out (h2 never materialized): single-graph blocks (~99.5%,
//    batch sorted) accumulate into an LDS bin and flush 128 fp32 atomics;
//    boundary blocks flush per-node.
template <bool POOL>
__global__ __launch_bounds__(256) void aggregate(const unsigned short* __restrict__ xw,
                                                 const float* __restrict__ dinv,
                                                 const int* __restrict__ start,
                                                 const int* __restrict__ cnt,
                                                 const int2* __restrict__ edata,
                                                 const float* __restrict__ bvec,
                                                 unsigned short* __restrict__ out,
                                                 const int* __restrict__ batch,
                                                 float* __restrict__ pooled, int N) {
    __shared__ float pool_sh[FDIM];
    if (POOL && threadIdx.x < FDIM) pool_sh[threadIdx.x] = 0.f;
    if (POOL) __syncthreads();

    const int base = blockIdx.x * 16;
    const int node = base + (threadIdx.x >> 4);
    const int l8 = threadIdx.x & 15;  // 8-col group
    const bool active = node < N;
    const int nidx = active ? node : (N - 1);

    float dv = dinv[nidx];
    float d2 = dv * dv;
    float4 b0 = ((const float4*)bvec)[l8 * 2];
    float4 b1 = ((const float4*)bvec)[l8 * 2 + 1];
    float acc[8] = {b0.x, b0.y, b0.z, b0.w, b1.x, b1.y, b1.z, b1.w};
    short8 sv = *(const short8*)&xw[(size_t)nidx * FDIM + l8 * 8];
    bf8_fma(sv, d2, acc);

    int j = start[nidx];
    const int s1 = j + (active ? cnt[nidx] : 0);
    for (; j + 4 <= s1; j += 4) {
        int2 e0 = edata[j], e1 = edata[j + 1], e2 = edata[j + 2], e3 = edata[j + 3];
        short8 u0 = *(const short8*)&xw[(size_t)e0.x * FDIM + l8 * 8];
        short8 u1 = *(const short8*)&xw[(size_t)e1.x * FDIM + l8 * 8];
        short8 u2 = *(const short8*)&xw[(size_t)e2.x * FDIM + l8 * 8];
        short8 u3 = *(const short8*)&xw[(size_t)e3.x * FDIM + l8 * 8];
        bf8_fma(u0, __int_as_float(e0.y), acc);
        bf8_fma(u1, __int_as_float(e1.y), acc);
        bf8_fma(u2, __int_as_float(e2.y), acc);
        bf8_fma(u3, __int_as_float(e3.y), acc);
    }
    for (; j < s1; ++j) {
        int2 ed = edata[j];
        short8 u = *(const short8*)&xw[(size_t)ed.x * FDIM + l8 * 8];
        bf8_fma(u, __int_as_float(ed.y), acc);
    }

    if (!POOL) {
        short8 o;
#pragma unroll
        for (int k = 0; k < 8; ++k)
            ((unsigned short*)&o)[k] = f2bf(fmaxf(acc[k], 0.f));
        if (active) *(short8*)&out[(size_t)node * FDIM + l8 * 8] = o;
    } else {
        float r[8];
#pragma unroll
        for (int k = 0; k < 8; ++k) r[k] = fmaxf(acc[k], 0.f);
        int g0 = batch[base];
        int g1 = batch[min(base + 15, N - 1)];
        if (g0 == g1) {  // block-uniform branch — safe around __syncthreads
            if (active) {
#pragma unroll
                for (int k = 0; k < 8; ++k) atomicAdd(&pool_sh[l8 * 8 + k], r[k]);
            }
            __syncthreads();
            if (threadIdx.x < FDIM)
                unsafeAtomicAdd(&pooled[g0 * FDIM + threadIdx.x], pool_sh[threadIdx.x]);
        } else {
            if (active) {
                int g = batch[node];
#pragma unroll
                for (int k = 0; k < 8; ++k)
                    unsafeAtomicAdd(&pooled[g * FDIM + l8 * 8 + k], r[k]);
            }
        }
    }
}

// ---------------------------------------------------------------------------
extern "C" void kernel_launch(void* const* d_in, const int* in_sizes, int n_in,
                              void* d_out, int out_size, void* d_ws, size_t ws_size,
                              hipStream_t stream) {
    const float* x = (const float*)d_in[0];
    const int* ei = (const int*)d_in[1];
    const int* batch = (const int*)d_in[2];
    const float* W1 = (const float*)d_in[4];
    const float* b1 = (const float*)d_in[5];
    const float* W2 = (const float*)d_in[6];
    const float* b2 = (const float*)d_in[7];

    const int N = in_sizes[2];
    const int E = in_sizes[1] / 2;
    const int* srcp = ei;
    const int* dstp = ei + E;

    const size_t NF = (size_t)N * FDIM;
    unsigned short* bufA = (unsigned short*)d_ws;  // N*128 bf16 (xw)
    unsigned short* bufB = bufA + NF;              // N*128 bf16 (h1)
    int* cnt = (int*)(bufB + NF);                  // N      <- memset from here
    int* counter = cnt + N;                        // 4
    float* bias0 = (float*)(counter + 4);          // 128    <- memset to here
    float* dinv = bias0 + FDIM;                    // N
    int* start = (int*)(dinv + N);                 // N
    int* wcur = start + N;                         // N
    unsigned short* WT1 = (unsigned short*)(wcur + N);  // 128*128 bf16
    unsigned short* WT2 = WT1 + FDIM * FDIM;            // 128*128 bf16
    int2* edata = (int2*)(WT2 + FDIM * FDIM);      // E x {src, coef}
    float* partials = (float*)edata;               // aliased; dead before fill_edges
    const int STAT_BLOCKS = 512;

    hipMemsetAsync(cnt, 0, ((size_t)N + 4 + FDIM) * sizeof(int), stream);
    hipMemsetAsync(d_out, 0, (size_t)out_size * sizeof(float), stream);

    const int degBlocks = (E + 255) / 256;
    pre_combo<<<STAT_BLOCKS + degBlocks, 256, 0, stream>>>(x, N, partials, STAT_BLOCKS,
                                                           dstp, E, cnt);
    stats_prep<<<16, 256, 0, stream>>>(partials, STAT_BLOCKS, N, W1, W2, WT1, WT2, bias0);
    alloc_offsets<<<(N + 255) / 256, 256, 0, stream>>>(cnt, N, start, wcur, counter, dinv);
    fill_edges<<<degBlocks, 256, 0, stream>>>(srcp, dstp, dinv, E, wcur, edata);

    const int gemmGrid = (N + 63) / 64;
    const int aggGrid = (N + 15) / 16;

    // ---- layer 1 (standardization folded into WT1/bias0; relu in aggregate)
    gemm_mfma<float><<<gemmGrid, 256, 0, stream>>>(x, WT1, bias0, bufA, N);
    aggregate<false><<<aggGrid, 256, 0, stream>>>(bufA, dinv, start, cnt, edata, b1,
                                                  bufB, nullptr, nullptr, N);

    // ---- layer 2 + pool fused (h2 never materialized)
    gemm_mfma<unsigned short><<<gemmGrid, 256, 0, stream>>>(bufB, WT2, nullptr, bufA, N);
    aggregate<true><<<aggGrid, 256, 0, stream>>>(bufA, dinv, start, cnt, edata, b2,
                                                 nullptr, batch, (float*)d_out, N);
}

// Round 8
// 490.660 us; speedup vs baseline: 1.1900x; 1.1900x over previous
//
#include <hip/hip_runtime.h>

#define FDIM 128  // feature dim == hidden dim

typedef __attribute__((ext_vector_type(8))) short short8;   // 8 bf16 (4 VGPRs)
typedef __attribute__((ext_vector_type(4))) float f32x4;    // MFMA accumulator

__device__ inline unsigned short f2bf(float f) {  // round-to-nearest-even
    unsigned int u = __float_as_uint(f);
    unsigned int r = u + 0x7FFFu + ((u >> 16) & 1u);
    return (unsigned short)(r >> 16);
}
__device__ inline float bf2f(unsigned short b) {
    return __uint_as_float((unsigned int)b << 16);
}
__device__ inline void bf8_fma(short8 v, float c, float* acc) {
#pragma unroll
    for (int k = 0; k < 8; ++k)
        acc[k] = fmaf(bf2f(((const unsigned short*)&v)[k]), c, acc[k]);
}

// ---------------------------------------------------------------------------
// 1) heterogeneous pre-pass: blocks [0,statBlocks) = column sum/sumsq partials
//    (BW-bound sweep of x); blocks >= statBlocks = dst-degree atomics
//    (latency-bound) — merged so the two run concurrently.
__global__ __launch_bounds__(256) void pre_combo(const float* __restrict__ x, int N,
                                                 float* __restrict__ partials, int statBlocks,
                                                 const int* __restrict__ dst, int E,
                                                 int* __restrict__ cnt) {
    if ((int)blockIdx.x >= statBlocks) {
        int e = (blockIdx.x - statBlocks) * 256 + threadIdx.x;
        if (e < E) atomicAdd(&cnt[dst[e]], 1);
        return;
    }
    const int c4 = threadIdx.x & 31;
    const int rg = threadIdx.x >> 5;
    float4 s = make_float4(0.f, 0.f, 0.f, 0.f);
    float4 q = make_float4(0.f, 0.f, 0.f, 0.f);
    for (long r = (long)blockIdx.x * 8 + rg; r < N; r += (long)statBlocks * 8) {
        float4 v = ((const float4*)x)[r * 32 + c4];
        s.x += v.x; s.y += v.y; s.z += v.z; s.w += v.w;
        q.x += v.x * v.x; q.y += v.y * v.y; q.z += v.z * v.z; q.w += v.w * v.w;
    }
    __shared__ float red[8][32][8];
    float* p = red[rg][c4];
    p[0] = s.x; p[1] = s.y; p[2] = s.z; p[3] = s.w;
    p[4] = q.x; p[5] = q.y; p[6] = q.z; p[7] = q.w;
    __syncthreads();
    if (rg == 0) {
#pragma unroll
        for (int g = 1; g < 8; ++g) {
            const float* o = red[g][c4];
#pragma unroll
            for (int j = 0; j < 8; ++j) red[0][c4][j] += o[j];
        }
        const float* r0 = red[0][c4];
        float* out = &partials[(size_t)blockIdx.x * 256];
        ((float4*)out)[c4] = make_float4(r0[0], r0[1], r0[2], r0[3]);
        ((float4*)(out + 128))[c4] = make_float4(r0[4], r0[5], r0[6], r0[7]);
    }
}

// ---------------------------------------------------------------------------
// 2) fused stats-reduce + weight transpose. 16 blocks; each redundantly
//    reduces partials (L2-hit) into mean/rstd, then transposes its j-slice.
__global__ __launch_bounds__(256) void stats_prep(const float* __restrict__ partials,
                                                  int nblk, int N,
                                                  const float* __restrict__ W1,
                                                  const float* __restrict__ W2,
                                                  unsigned short* __restrict__ WT1,
                                                  unsigned short* __restrict__ WT2,
                                                  float* __restrict__ bias0) {
    __shared__ float mean_sh[FDIM], rstd_sh[FDIM];
    __shared__ float red[2][2][FDIM];
    const int half = threadIdx.x >> 7;  // 0,1
    const int j = threadIdx.x & 127;
    float s = 0.f, q = 0.f;
    for (int b = half; b < nblk; b += 2) {
        s += partials[(size_t)b * 256 + j];
        q += partials[(size_t)b * 256 + 128 + j];
    }
    red[half][0][j] = s;
    red[half][1][j] = q;
    __syncthreads();
    if (half == 0) {
        s += red[1][0][j];
        q += red[1][1][j];
        float m = s / (float)N;
        float var = (q - (float)N * m * m) / (float)(N - 1);
        mean_sh[j] = m;
        rstd_sh[j] = rsqrtf(var);
    }
    __syncthreads();

    const int b = blockIdx.x;
    const int h = j;
    const int jbase0 = (threadIdx.x >> 7) * 8;
    if (b < 8) {
        float acc = 0.f;
#pragma unroll
        for (int jj = 0; jj < 8; ++jj) {
            int j2 = b * 16 + jbase0 + jj;
            float w = W1[j2 * FDIM + h] * rstd_sh[j2];
            WT1[h * FDIM + j2] = f2bf(w);
            acc += mean_sh[j2] * w;
        }
        unsafeAtomicAdd(&bias0[h], -acc);
    } else {
#pragma unroll
        for (int jj = 0; jj < 8; ++jj) {
            int j2 = (b - 8) * 16 + jbase0 + jj;
            WT2[h * FDIM + j2] = f2bf(W2[j2 * FDIM + h]);
        }
    }
}

// ---------------------------------------------------------------------------
// 3) contiguous per-node edge ranges + dinv (fused)
__global__ __launch_bounds__(256) void alloc_offsets(const int* __restrict__ cnt, int N,
                                                     int* __restrict__ start,
                                                     int* __restrict__ wcur,
                                                     int* __restrict__ counter,
                                                     float* __restrict__ dinv) {
    __shared__ int sh[256];
    __shared__ int base;
    int i = blockIdx.x * 256 + threadIdx.x;
    int v = (i < N) ? cnt[i] : 0;
    sh[threadIdx.x] = v;
    __syncthreads();
    for (int off = 1; off < 256; off <<= 1) {
        int t = (threadIdx.x >= off) ? sh[threadIdx.x - off] : 0;
        __syncthreads();
        sh[threadIdx.x] += t;
        __syncthreads();
    }
    if (threadIdx.x == 255) base = atomicAdd(counter, sh[255]);
    __syncthreads();
    int excl = base + sh[threadIdx.x] - v;
    if (i < N) {
        start[i] = excl;
        wcur[i] = excl;
        dinv[i] = rsqrtf((float)v + 1.0f);
    }
}

// 4) bucket edges by dst; one 8B store per edge: {src, coef bits}
__global__ void fill_edges(const int* __restrict__ src, const int* __restrict__ dst,
                           const float* __restrict__ dinv, int E,
                           int* __restrict__ wcur, int2* __restrict__ edata) {
    int e = blockIdx.x * blockDim.x + threadIdx.x;
    if (e >= E) return;
    int s = src[e], d = dst[e];
    int pos = atomicAdd(&wcur[d], 1);
    edata[pos] = make_int2(s, __float_as_int(dinv[s] * dinv[d]));
}

// ---------------------------------------------------------------------------
// 5) bf16 MFMA GEMM: C_bf16[M x 128] = A[M x 128] @ W[128 x 128] (+ bias)
template <typename T>
__global__ __launch_bounds__(256) void gemm_mfma(const T* __restrict__ A,
                                                 const unsigned short* __restrict__ WT,
                                                 const float* __restrict__ bias,
                                                 unsigned short* __restrict__ C, int M) {
    constexpr int LDA = 136;
    __shared__ unsigned short Alds[64 * LDA];
    __shared__ unsigned short Wlds[FDIM * LDA];
    const int tid = threadIdx.x;
    const int row0 = blockIdx.x * 64;

    for (int i = tid; i < FDIM * 16; i += 256) {
        int r = i >> 4, g = i & 15;
        *(int4*)&Wlds[r * LDA + g * 8] = *(const int4*)&WT[r * FDIM + g * 8];
    }
    if constexpr (sizeof(T) == 4) {
        for (int i = tid; i < 64 * 32; i += 256) {
            int r = i >> 5, c4 = i & 31;
            int row = row0 + r;
            float4 v = make_float4(0.f, 0.f, 0.f, 0.f);
            if (row < M) v = ((const float4*)A)[(size_t)row * 32 + c4];
            ushort4 p;
            p.x = f2bf(v.x); p.y = f2bf(v.y); p.z = f2bf(v.z); p.w = f2bf(v.w);
            *(ushort4*)&Alds[r * LDA + c4 * 4] = p;
        }
    } else {
        for (int i = tid; i < 64 * 16; i += 256) {
            int r = i >> 4, g = i & 15;
            int row = row0 + r;
            int4 v = make_int4(0, 0, 0, 0);
            if (row < M) v = *(const int4*)&A[(size_t)row * FDIM + g * 8];
            *(int4*)&Alds[r * LDA + g * 8] = v;
        }
    }
    __syncthreads();

    const int lane = tid & 63;
    const int wave = tid >> 6;
    const int m16 = lane & 15;
    const int quad = lane >> 4;

    f32x4 acc[8];
#pragma unroll
    for (int t = 0; t < 8; ++t) acc[t] = (f32x4){0.f, 0.f, 0.f, 0.f};

    const unsigned short* Abase = &Alds[(wave * 16 + m16) * LDA + quad * 8];
    const unsigned short* Wbase = &Wlds[m16 * LDA + quad * 8];
#pragma unroll
    for (int s = 0; s < 4; ++s) {
        short8 a = *(const short8*)&Abase[s * 32];
#pragma unroll
        for (int t = 0; t < 8; ++t) {
            short8 b = *(const short8*)&Wbase[t * 16 * LDA + s * 32];
            acc[t] = __builtin_amdgcn_mfma_f32_16x16x32_bf16(a, b, acc[t], 0, 0, 0);
        }
    }

#pragma unroll
    for (int t = 0; t < 8; ++t) {
        float bv = bias ? bias[t * 16 + m16] : 0.f;
#pragma unroll
        for (int i = 0; i < 4; ++i) {
            int r = row0 + wave * 16 + quad * 4 + i;
            if (r < M) C[(size_t)r * FDIM + t * 16 + m16] = f2bf(acc[t][i] + bv);
        }
    }
}

// ---------------------------------------------------------------------------
// 6) aggregation (bf16 in, fp32 accum, relu). 16 lanes/node, 16 nodes/block,
//    4x-unrolled edge loop.
//    POOL=false: store bf16 rows (round-6 form, early return).
//    POOL=true: pool into per-block PARTIALS via plain LDS writes + tree
//    reduce + one coalesced 512B store/block (NO global atomic storm — round
//    7's 1.6M atomics onto 512 L2 lines stalled the whole vmem pipeline).
//    Graph-boundary blocks (~63/12500, batch sorted) fall back to direct
//    per-node atomics and tag their slot -1.
template <bool POOL>
__global__ __launch_bounds__(256) void aggregate(const unsigned short* __restrict__ xw,
                                                 const float* __restrict__ dinv,
                                                 const int* __restrict__ start,
                                                 const int* __restrict__ cnt,
                                                 const int2* __restrict__ edata,
                                                 const float* __restrict__ bvec,
                                                 unsigned short* __restrict__ out,
                                                 const int* __restrict__ batch,
                                                 float* __restrict__ pool_part,
                                                 int* __restrict__ ptag,
                                                 float* __restrict__ pooled, int N) {
    const int base = blockIdx.x * 16;
    const int node = base + (threadIdx.x >> 4);
    const int l8 = threadIdx.x & 15;  // 8-col group
    const bool active = node < N;
    if (!POOL && !active) return;
    const int nidx = active ? node : (N - 1);

    float dv = dinv[nidx];
    float d2 = dv * dv;
    float4 b0 = ((const float4*)bvec)[l8 * 2];
    float4 b1 = ((const float4*)bvec)[l8 * 2 + 1];
    float acc[8] = {b0.x, b0.y, b0.z, b0.w, b1.x, b1.y, b1.z, b1.w};
    short8 sv = *(const short8*)&xw[(size_t)nidx * FDIM + l8 * 8];
    bf8_fma(sv, d2, acc);

    int j = start[nidx];
    const int s1 = j + (active ? cnt[nidx] : 0);
    for (; j + 4 <= s1; j += 4) {
        int2 e0 = edata[j], e1 = edata[j + 1], e2 = edata[j + 2], e3 = edata[j + 3];
        short8 u0 = *(const short8*)&xw[(size_t)e0.x * FDIM + l8 * 8];
        short8 u1 = *(const short8*)&xw[(size_t)e1.x * FDIM + l8 * 8];
        short8 u2 = *(const short8*)&xw[(size_t)e2.x * FDIM + l8 * 8];
        short8 u3 = *(const short8*)&xw[(size_t)e3.x * FDIM + l8 * 8];
        bf8_fma(u0, __int_as_float(e0.y), acc);
        bf8_fma(u1, __int_as_float(e1.y), acc);
        bf8_fma(u2, __int_as_float(e2.y), acc);
        bf8_fma(u3, __int_as_float(e3.y), acc);
    }
    for (; j < s1; ++j) {
        int2 ed = edata[j];
        short8 u = *(const short8*)&xw[(size_t)ed.x * FDIM + l8 * 8];
        bf8_fma(u, __int_as_float(ed.y), acc);
    }

    if constexpr (!POOL) {
        short8 o;
#pragma unroll
        for (int k = 0; k < 8; ++k)
            ((unsigned short*)&o)[k] = f2bf(fmaxf(acc[k], 0.f));
        *(short8*)&out[(size_t)node * FDIM + l8 * 8] = o;
    } else {
        float r[8];
#pragma unroll
        for (int k = 0; k < 8; ++k) r[k] = active ? fmaxf(acc[k], 0.f) : 0.f;
        int g0 = batch[base];
        int g1 = batch[min(base + 15, N - 1)];
        if (g0 == g1) {  // block-uniform branch — safe around __syncthreads
            __shared__ float red[16][FDIM];  // 8 KB; plain writes, no LDS atomics
            float* dst = &red[threadIdx.x >> 4][l8 * 8];
            *(float4*)dst = make_float4(r[0], r[1], r[2], r[3]);
            *(float4*)(dst + 4) = make_float4(r[4], r[5], r[6], r[7]);
            __syncthreads();
            if (threadIdx.x < FDIM) {
                float s = 0.f;
#pragma unroll
                for (int i = 0; i < 16; ++i) s += red[i][threadIdx.x];
                pool_part[(size_t)blockIdx.x * FDIM + threadIdx.x] = s;
                if (threadIdx.x == 0) ptag[blockIdx.x] = g0;
            }
        } else {  // rare boundary block: direct atomics, slot skipped
            if (threadIdx.x == 0) ptag[blockIdx.x] = -1;
            if (active) {
                int g = batch[node];
#pragma unroll
                for (int k = 0; k < 8; ++k)
                    unsafeAtomicAdd(&pooled[g * FDIM + l8 * 8 + k], r[k]);
            }
        }
    }
}

// ---------------------------------------------------------------------------
// 7) reduce tagged per-block pool partials into d_out. Tags are monotone
//    (batch sorted, blocks in node order); -1 slots already flushed directly.
//    Running accumulate + flush-on-change: ~1-2 flushes of 128 atomics/block.
__global__ __launch_bounds__(128) void pool_reduce(const float* __restrict__ pool_part,
                                                   const int* __restrict__ ptag,
                                                   int nslots, float* __restrict__ out) {
    int per = (nslots + gridDim.x - 1) / gridDim.x;
    int s0 = blockIdx.x * per;
    int s1 = min(s0 + per, nslots);
    int t = threadIdx.x;
    float acc = 0.f;
    int cur = -1;
    for (int s = s0; s < s1; ++s) {
        int g = ptag[s];  // broadcast scalar load
        if (g < 0) continue;
        if (g != cur) {
            if (cur >= 0) unsafeAtomicAdd(&out[cur * FDIM + t], acc);
            acc = 0.f;
            cur = g;
        }
        acc += pool_part[(size_t)s * FDIM + t];
    }
    if (cur >= 0) unsafeAtomicAdd(&out[cur * FDIM + t], acc);
}

// ---------------------------------------------------------------------------
extern "C" void kernel_launch(void* const* d_in, const int* in_sizes, int n_in,
                              void* d_out, int out_size, void* d_ws, size_t ws_size,
                              hipStream_t stream) {
    const float* x = (const float*)d_in[0];
    const int* ei = (const int*)d_in[1];
    const int* batch = (const int*)d_in[2];
    const float* W1 = (const float*)d_in[4];
    const float* b1 = (const float*)d_in[5];
    const float* W2 = (const float*)d_in[6];
    const float* b2 = (const float*)d_in[7];

    const int N = in_sizes[2];
    const int E = in_sizes[1] / 2;
    const int* srcp = ei;
    const int* dstp = ei + E;

    const size_t NF = (size_t)N * FDIM;
    const int aggGrid = (N + 15) / 16;
    unsigned short* bufA = (unsigned short*)d_ws;  // N*128 bf16 (xw)
    unsigned short* bufB = bufA + NF;              // N*128 bf16 (h1)
    int* cnt = (int*)(bufB + NF);                  // N      <- memset from here
    int* counter = cnt + N;                        // 4
    float* bias0 = (float*)(counter + 4);          // 128    <- memset to here
    float* dinv = bias0 + FDIM;                    // N
    int* start = (int*)(dinv + N);                 // N
    int* wcur = start + N;                         // N
    unsigned short* WT1 = (unsigned short*)(wcur + N);  // 128*128 bf16
    unsigned short* WT2 = WT1 + FDIM * FDIM;            // 128*128 bf16
    int2* edata = (int2*)(WT2 + FDIM * FDIM);      // E x {src, coef}
    float* pool_part = (float*)(edata + E);        // aggGrid*128 f32
    int* ptag = (int*)(pool_part + (size_t)aggGrid * FDIM);  // aggGrid
    float* partials = (float*)edata;               // aliased; dead before fill_edges
    const int STAT_BLOCKS = 512;

    hipMemsetAsync(cnt, 0, ((size_t)N + 4 + FDIM) * sizeof(int), stream);
    hipMemsetAsync(d_out, 0, (size_t)out_size * sizeof(float), stream);

    const int degBlocks = (E + 255) / 256;
    pre_combo<<<STAT_BLOCKS + degBlocks, 256, 0, stream>>>(x, N, partials, STAT_BLOCKS,
                                                           dstp, E, cnt);
    stats_prep<<<16, 256, 0, stream>>>(partials, STAT_BLOCKS, N, W1, W2, WT1, WT2, bias0);
    alloc_offsets<<<(N + 255) / 256, 256, 0, stream>>>(cnt, N, start, wcur, counter, dinv);
    fill_edges<<<degBlocks, 256, 0, stream>>>(srcp, dstp, dinv, E, wcur, edata);

    const int gemmGrid = (N + 63) / 64;

    // ---- layer 1 (standardization folded into WT1/bias0; relu in aggregate)
    gemm_mfma<float><<<gemmGrid, 256, 0, stream>>>(x, WT1, bias0, bufA, N);
    aggregate<false><<<aggGrid, 256, 0, stream>>>(bufA, dinv, start, cnt, edata, b1,
                                                  bufB, nullptr, nullptr, nullptr,
                                                  nullptr, N);

    // ---- layer 2 + pool fused (h2 never materialized; atomic-free partials)
    gemm_mfma<unsigned short><<<gemmGrid, 256, 0, stream>>>(bufB, WT2, nullptr, bufA, N);
    aggregate<true><<<aggGrid, 256, 0, stream>>>(bufA, dinv, start, cnt, edata, b2,
                                                 nullptr, batch, pool_part, ptag,
                                                 (float*)d_out, N);
    pool_reduce<<<256, 128, 0, stream>>>(pool_part, ptag, aggGrid, (float*)d_out);
}

// Round 9
// 404.701 us; speedup vs baseline: 1.4428x; 1.2124x over previous
//
#include <hip/hip_runtime.h>

#define FDIM 128  // feature dim == hidden dim

typedef __attribute__((ext_vector_type(8))) short short8;   // 8 bf16 (4 VGPRs)
typedef __attribute__((ext_vector_type(4))) float f32x4;    // MFMA accumulator

__device__ inline unsigned short f2bf(float f) {  // round-to-nearest-even
    unsigned int u = __float_as_uint(f);
    unsigned int r = u + 0x7FFFu + ((u >> 16) & 1u);
    return (unsigned short)(r >> 16);
}
__device__ inline float bf2f(unsigned short b) {
    return __uint_as_float((unsigned int)b << 16);
}
__device__ inline void bf8_fma(short8 v, float c, float* acc) {
#pragma unroll
    for (int k = 0; k < 8; ++k)
        acc[k] = fmaf(bf2f(((const unsigned short*)&v)[k]), c, acc[k]);
}

// ---------------------------------------------------------------------------
// 1) heterogeneous pre-pass: blocks [0,statBlocks) = column sum/sumsq partials
//    (BW-bound sweep of x); blocks >= statBlocks = dst-degree atomics
//    (latency-bound) — merged so the two run concurrently.
__global__ __launch_bounds__(256) void pre_combo(const float* __restrict__ x, int N,
                                                 float* __restrict__ partials, int statBlocks,
                                                 const int* __restrict__ dst, int E,
                                                 int* __restrict__ cnt) {
    if ((int)blockIdx.x >= statBlocks) {
        int e = (blockIdx.x - statBlocks) * 256 + threadIdx.x;
        if (e < E) atomicAdd(&cnt[dst[e]], 1);
        return;
    }
    const int c4 = threadIdx.x & 31;
    const int rg = threadIdx.x >> 5;
    float4 s = make_float4(0.f, 0.f, 0.f, 0.f);
    float4 q = make_float4(0.f, 0.f, 0.f, 0.f);
    for (long r = (long)blockIdx.x * 8 + rg; r < N; r += (long)statBlocks * 8) {
        float4 v = ((const float4*)x)[r * 32 + c4];
        s.x += v.x; s.y += v.y; s.z += v.z; s.w += v.w;
        q.x += v.x * v.x; q.y += v.y * v.y; q.z += v.z * v.z; q.w += v.w * v.w;
    }
    __shared__ float red[8][32][8];
    float* p = red[rg][c4];
    p[0] = s.x; p[1] = s.y; p[2] = s.z; p[3] = s.w;
    p[4] = q.x; p[5] = q.y; p[6] = q.z; p[7] = q.w;
    __syncthreads();
    if (rg == 0) {
#pragma unroll
        for (int g = 1; g < 8; ++g) {
            const float* o = red[g][c4];
#pragma unroll
            for (int j = 0; j < 8; ++j) red[0][c4][j] += o[j];
        }
        const float* r0 = red[0][c4];
        float* out = &partials[(size_t)blockIdx.x * 256];
        ((float4*)out)[c4] = make_float4(r0[0], r0[1], r0[2], r0[3]);
        ((float4*)(out + 128))[c4] = make_float4(r0[4], r0[5], r0[6], r0[7]);
    }
}

// ---------------------------------------------------------------------------
// 2) mid_combo: blocks [0, offsBlocks) = per-node edge-range scan + dinv;
//    blocks offsBlocks..+8 = W1 stats-slice reduce + scaled transpose + bias0;
//    blocks +8..+16 = W2 transpose. (All independent given pre_combo done.)
//    Round 8's stats_prep burned 69us: 16 blocks x 256 scalar strided loads
//    each — here every W1 block reduces ONLY its 32-col slice with float4
//    loads (16 independent loads/thread).
__global__ __launch_bounds__(256) void mid_combo(const int* __restrict__ cnt, int N,
                                                 int* __restrict__ start,
                                                 int* __restrict__ wcur,
                                                 int* __restrict__ counter,
                                                 float* __restrict__ dinv,
                                                 const float* __restrict__ partials,
                                                 int nblk, int offsBlocks,
                                                 const float* __restrict__ W1,
                                                 const float* __restrict__ W2,
                                                 unsigned short* __restrict__ WT1,
                                                 unsigned short* __restrict__ WT2,
                                                 float* __restrict__ bias0) {
    const int tid = threadIdx.x;
    if ((int)blockIdx.x < offsBlocks) {
        __shared__ int sh[256];
        __shared__ int base;
        int i = blockIdx.x * 256 + tid;
        int v = (i < N) ? cnt[i] : 0;
        sh[tid] = v;
        __syncthreads();
        for (int off = 1; off < 256; off <<= 1) {
            int t = (tid >= off) ? sh[tid - off] : 0;
            __syncthreads();
            sh[tid] += t;
            __syncthreads();
        }
        if (tid == 255) base = atomicAdd(counter, sh[255]);
        __syncthreads();
        int excl = base + sh[tid] - v;
        if (i < N) {
            start[i] = excl;
            wcur[i] = excl;
            dinv[i] = rsqrtf((float)v + 1.0f);
        }
        return;
    }
    const int b = blockIdx.x - offsBlocks;  // 0..15
    const int h = tid & 127;
    const int seg = tid >> 7;  // 0,1
    if (b < 8) {
        // reduce this block's 32-col slice: 16 sum cols + 16 sumsq cols
        __shared__ float red[32][32];  // [rowgroup][localcol] 4 KB
        __shared__ float scol[32], mean_sh[16], rstd_sh[16];
        const int rg = tid >> 3;      // 0..31
        const int f = tid & 7;        // 0..7
        const int colbase = (f < 4) ? (b * 16 + f * 4) : (128 + b * 16 + (f - 4) * 4);
        float4 a = make_float4(0.f, 0.f, 0.f, 0.f);
        for (int row = rg; row < nblk; row += 32) {
            float4 v = *(const float4*)&partials[(size_t)row * 256 + colbase];
            a.x += v.x; a.y += v.y; a.z += v.z; a.w += v.w;
        }
        *(float4*)&red[rg][f * 4] = a;  // localcol f*4..+3 (0-15 sum, 16-31 sumsq)
        __syncthreads();
        if (tid < 32) {
            float s = 0.f;
#pragma unroll
            for (int r = 0; r < 32; ++r) s += red[r][tid];
            scol[tid] = s;
        }
        __syncthreads();
        if (tid < 16) {
            float m = scol[tid] / (float)N;
            float var = (scol[16 + tid] - (float)N * m * m) / (float)(N - 1);
            mean_sh[tid] = m;
            rstd_sh[tid] = rsqrtf(var);
        }
        __syncthreads();
        float acc = 0.f;
#pragma unroll
        for (int jj = 0; jj < 8; ++jj) {
            int jl = seg * 8 + jj;
            int j2 = b * 16 + jl;
            float w = W1[j2 * FDIM + h] * rstd_sh[jl];
            WT1[h * FDIM + j2] = f2bf(w);
            acc += mean_sh[jl] * w;
        }
        unsafeAtomicAdd(&bias0[h], -acc);
    } else {
#pragma unroll
        for (int jj = 0; jj < 8; ++jj) {
            int j2 = (b - 8) * 16 + seg * 8 + jj;
            WT2[h * FDIM + j2] = f2bf(W2[j2 * FDIM + h]);
        }
    }
}

// ---------------------------------------------------------------------------
// 3) GEMM1 + edge-bucketing merged: blocks [0,gemmBlocks) do the bf16 MFMA
//    GEMM (fp32 x input, standardization folded into WT1/bias0); blocks
//    beyond do fill_edges (latency-bound atomics, overlapped with GEMM).
__global__ __launch_bounds__(256) void gemm1_fill(const float* __restrict__ A,
                                                  const unsigned short* __restrict__ WT,
                                                  const float* __restrict__ bias,
                                                  unsigned short* __restrict__ C, int M,
                                                  int gemmBlocks,
                                                  const int* __restrict__ src,
                                                  const int* __restrict__ dst,
                                                  const float* __restrict__ dinv,
                                                  int* __restrict__ wcur,
                                                  int2* __restrict__ edata, int E) {
    const int tid = threadIdx.x;
    if ((int)blockIdx.x >= gemmBlocks) {
        int e = (blockIdx.x - gemmBlocks) * 256 + tid;
        if (e < E) {
            int s = src[e], d = dst[e];
            int pos = atomicAdd(&wcur[d], 1);
            edata[pos] = make_int2(s, __float_as_int(dinv[s] * dinv[d]));
        }
        return;
    }
    constexpr int LDA = 136;
    __shared__ unsigned short Alds[64 * LDA];
    __shared__ unsigned short Wlds[FDIM * LDA];
    const int row0 = blockIdx.x * 64;

    for (int i = tid; i < FDIM * 16; i += 256) {
        int r = i >> 4, g = i & 15;
        *(int4*)&Wlds[r * LDA + g * 8] = *(const int4*)&WT[r * FDIM + g * 8];
    }
    for (int i = tid; i < 64 * 32; i += 256) {
        int r = i >> 5, c4 = i & 31;
        int row = row0 + r;
        float4 v = make_float4(0.f, 0.f, 0.f, 0.f);
        if (row < M) v = ((const float4*)A)[(size_t)row * 32 + c4];
        ushort4 p;
        p.x = f2bf(v.x); p.y = f2bf(v.y); p.z = f2bf(v.z); p.w = f2bf(v.w);
        *(ushort4*)&Alds[r * LDA + c4 * 4] = p;
    }
    __syncthreads();

    const int lane = tid & 63;
    const int wave = tid >> 6;
    const int m16 = lane & 15;
    const int quad = lane >> 4;

    f32x4 acc[8];
#pragma unroll
    for (int t = 0; t < 8; ++t) acc[t] = (f32x4){0.f, 0.f, 0.f, 0.f};

    const unsigned short* Abase = &Alds[(wave * 16 + m16) * LDA + quad * 8];
    const unsigned short* Wbase = &Wlds[m16 * LDA + quad * 8];
#pragma unroll
    for (int s = 0; s < 4; ++s) {
        short8 a = *(const short8*)&Abase[s * 32];
#pragma unroll
        for (int t = 0; t < 8; ++t) {
            short8 b = *(const short8*)&Wbase[t * 16 * LDA + s * 32];
            acc[t] = __builtin_amdgcn_mfma_f32_16x16x32_bf16(a, b, acc[t], 0, 0, 0);
        }
    }
#pragma unroll
    for (int t = 0; t < 8; ++t) {
        float bv = bias[t * 16 + m16];
#pragma unroll
        for (int i = 0; i < 4; ++i) {
            int r = row0 + wave * 16 + quad * 4 + i;
            if (r < M) C[(size_t)r * FDIM + t * 16 + m16] = f2bf(acc[t][i] + bv);
        }
    }
}

// ---------------------------------------------------------------------------
// 4) bf16 MFMA GEMM (layer 2: bf16 input, no bias)
__global__ __launch_bounds__(256) void gemm_mfma2(const unsigned short* __restrict__ A,
                                                  const unsigned short* __restrict__ WT,
                                                  unsigned short* __restrict__ C, int M) {
    constexpr int LDA = 136;
    __shared__ unsigned short Alds[64 * LDA];
    __shared__ unsigned short Wlds[FDIM * LDA];
    const int tid = threadIdx.x;
    const int row0 = blockIdx.x * 64;

    for (int i = tid; i < FDIM * 16; i += 256) {
        int r = i >> 4, g = i & 15;
        *(int4*)&Wlds[r * LDA + g * 8] = *(const int4*)&WT[r * FDIM + g * 8];
    }
    for (int i = tid; i < 64 * 16; i += 256) {
        int r = i >> 4, g = i & 15;
        int row = row0 + r;
        int4 v = make_int4(0, 0, 0, 0);
        if (row < M) v = *(const int4*)&A[(size_t)row * FDIM + g * 8];
        *(int4*)&Alds[r * LDA + g * 8] = v;
    }
    __syncthreads();

    const int lane = tid & 63;
    const int wave = tid >> 6;
    const int m16 = lane & 15;
    const int quad = lane >> 4;

    f32x4 acc[8];
#pragma unroll
    for (int t = 0; t < 8; ++t) acc[t] = (f32x4){0.f, 0.f, 0.f, 0.f};

    const unsigned short* Abase = &Alds[(wave * 16 + m16) * LDA + quad * 8];
    const unsigned short* Wbase = &Wlds[m16 * LDA + quad * 8];
#pragma unroll
    for (int s = 0; s < 4; ++s) {
        short8 a = *(const short8*)&Abase[s * 32];
#pragma unroll
        for (int t = 0; t < 8; ++t) {
            short8 b = *(const short8*)&Wbase[t * 16 * LDA + s * 32];
            acc[t] = __builtin_amdgcn_mfma_f32_16x16x32_bf16(a, b, acc[t], 0, 0, 0);
        }
    }
#pragma unroll
    for (int t = 0; t < 8; ++t) {
#pragma unroll
        for (int i = 0; i < 4; ++i) {
            int r = row0 + wave * 16 + quad * 4 + i;
            if (r < M) C[(size_t)r * FDIM + t * 16 + m16] = f2bf(acc[t][i]);
        }
    }
}

// ---------------------------------------------------------------------------
// 5) aggregation (bf16 in, fp32 accum, relu). 16 lanes/node, 16 nodes/block,
//    4x-unrolled edge loop. POOL=false: store bf16 rows. POOL=true: per-block
//    pool partial via plain LDS writes + tree reduce + one coalesced 512B
//    store (tag g0); boundary blocks (~63/12500) use direct atomics (tag -1).
template <bool POOL>
__global__ __launch_bounds__(256) void aggregate(const unsigned short* __restrict__ xw,
                                                 const float* __restrict__ dinv,
                                                 const int* __restrict__ start,
                                                 const int* __restrict__ cnt,
                                                 const int2* __restrict__ edata,
                                                 const float* __restrict__ bvec,
                                                 unsigned short* __restrict__ out,
                                                 const int* __restrict__ batch,
                                                 float* __restrict__ pool_part,
                                                 int* __restrict__ ptag,
                                                 float* __restrict__ pooled, int N) {
    const int base = blockIdx.x * 16;
    const int node = base + (threadIdx.x >> 4);
    const int l8 = threadIdx.x & 15;  // 8-col group
    const bool active = node < N;
    if (!POOL && !active) return;
    const int nidx = active ? node : (N - 1);

    float dv = dinv[nidx];
    float d2 = dv * dv;
    float4 b0 = ((const float4*)bvec)[l8 * 2];
    float4 b1 = ((const float4*)bvec)[l8 * 2 + 1];
    float acc[8] = {b0.x, b0.y, b0.z, b0.w, b1.x, b1.y, b1.z, b1.w};
    short8 sv = *(const short8*)&xw[(size_t)nidx * FDIM + l8 * 8];
    bf8_fma(sv, d2, acc);

    int j = start[nidx];
    const int s1 = j + (active ? cnt[nidx] : 0);
    for (; j + 4 <= s1; j += 4) {
        int2 e0 = edata[j], e1 = edata[j + 1], e2 = edata[j + 2], e3 = edata[j + 3];
        short8 u0 = *(const short8*)&xw[(size_t)e0.x * FDIM + l8 * 8];
        short8 u1 = *(const short8*)&xw[(size_t)e1.x * FDIM + l8 * 8];
        short8 u2 = *(const short8*)&xw[(size_t)e2.x * FDIM + l8 * 8];
        short8 u3 = *(const short8*)&xw[(size_t)e3.x * FDIM + l8 * 8];
        bf8_fma(u0, __int_as_float(e0.y), acc);
        bf8_fma(u1, __int_as_float(e1.y), acc);
        bf8_fma(u2, __int_as_float(e2.y), acc);
        bf8_fma(u3, __int_as_float(e3.y), acc);
    }
    for (; j < s1; ++j) {
        int2 ed = edata[j];
        short8 u = *(const short8*)&xw[(size_t)ed.x * FDIM + l8 * 8];
        bf8_fma(u, __int_as_float(ed.y), acc);
    }

    if constexpr (!POOL) {
        short8 o;
#pragma unroll
        for (int k = 0; k < 8; ++k)
            ((unsigned short*)&o)[k] = f2bf(fmaxf(acc[k], 0.f));
        *(short8*)&out[(size_t)node * FDIM + l8 * 8] = o;
    } else {
        float r[8];
#pragma unroll
        for (int k = 0; k < 8; ++k) r[k] = active ? fmaxf(acc[k], 0.f) : 0.f;
        int g0 = batch[base];
        int g1 = batch[min(base + 15, N - 1)];
        if (g0 == g1) {  // block-uniform branch — safe around __syncthreads
            __shared__ float red[16][FDIM];  // 8 KB; plain writes, no LDS atomics
            float* dst = &red[threadIdx.x >> 4][l8 * 8];
            *(float4*)dst = make_float4(r[0], r[1], r[2], r[3]);
            *(float4*)(dst + 4) = make_float4(r[4], r[5], r[6], r[7]);
            __syncthreads();
            if (threadIdx.x < FDIM) {
                float s = 0.f;
#pragma unroll
                for (int i = 0; i < 16; ++i) s += red[i][threadIdx.x];
                pool_part[(size_t)blockIdx.x * FDIM + threadIdx.x] = s;
                if (threadIdx.x == 0) ptag[blockIdx.x] = g0;
            }
        } else {  // rare boundary block: direct atomics, slot skipped
            if (threadIdx.x == 0) ptag[blockIdx.x] = -1;
            if (active) {
                int g = batch[node];
#pragma unroll
                for (int k = 0; k < 8; ++k)
                    unsafeAtomicAdd(&pooled[g * FDIM + l8 * 8 + k], r[k]);
            }
        }
    }
}

// ---------------------------------------------------------------------------
// 6) reduce tagged per-block pool partials into d_out (tags monotone).
__global__ __launch_bounds__(128) void pool_reduce(const float* __restrict__ pool_part,
                                                   const int* __restrict__ ptag,
                                                   int nslots, float* __restrict__ out) {
    int per = (nslots + gridDim.x - 1) / gridDim.x;
    int s0 = blockIdx.x * per;
    int s1 = min(s0 + per, nslots);
    int t = threadIdx.x;
    float acc = 0.f;
    int cur = -1;
    for (int s = s0; s < s1; ++s) {
        int g = ptag[s];  // broadcast scalar load
        if (g < 0) continue;
        if (g != cur) {
            if (cur >= 0) unsafeAtomicAdd(&out[cur * FDIM + t], acc);
            acc = 0.f;
            cur = g;
        }
        acc += pool_part[(size_t)s * FDIM + t];
    }
    if (cur >= 0) unsafeAtomicAdd(&out[cur * FDIM + t], acc);
}

// ---------------------------------------------------------------------------
extern "C" void kernel_launch(void* const* d_in, const int* in_sizes, int n_in,
                              void* d_out, int out_size, void* d_ws, size_t ws_size,
                              hipStream_t stream) {
    const float* x = (const float*)d_in[0];
    const int* ei = (const int*)d_in[1];
    const int* batch = (const int*)d_in[2];
    const float* W1 = (const float*)d_in[4];
    const float* b1 = (const float*)d_in[5];
    const float* W2 = (const float*)d_in[6];
    const float* b2 = (const float*)d_in[7];

    const int N = in_sizes[2];
    const int E = in_sizes[1] / 2;
    const int* srcp = ei;
    const int* dstp = ei + E;

    const size_t NF = (size_t)N * FDIM;
    const int aggGrid = (N + 15) / 16;
    unsigned short* bufA = (unsigned short*)d_ws;  // N*128 bf16 (xw)
    unsigned short* bufB = bufA + NF;              // N*128 bf16 (h1)
    int* cnt = (int*)(bufB + NF);                  // N      <- memset from here
    int* counter = cnt + N;                        // 4
    float* bias0 = (float*)(counter + 4);          // 128    <- memset to here
    float* dinv = bias0 + FDIM;                    // N
    int* start = (int*)(dinv + N);                 // N
    int* wcur = start + N;                         // N
    unsigned short* WT1 = (unsigned short*)(wcur + N);  // 128*128 bf16
    unsigned short* WT2 = WT1 + FDIM * FDIM;            // 128*128 bf16
    int2* edata = (int2*)(WT2 + FDIM * FDIM);      // E x {src, coef}
    float* pool_part = (float*)(edata + E);        // aggGrid*128 f32
    int* ptag = (int*)(pool_part + (size_t)aggGrid * FDIM);  // aggGrid
    float* partials = (float*)edata;               // aliased; dead before gemm1_fill
    const int STAT_BLOCKS = 512;

    hipMemsetAsync(cnt, 0, ((size_t)N + 4 + FDIM) * sizeof(int), stream);
    hipMemsetAsync(d_out, 0, (size_t)out_size * sizeof(float), stream);

    const int degBlocks = (E + 255) / 256;
    const int offsBlocks = (N + 255) / 256;
    const int gemmGrid = (N + 63) / 64;

    pre_combo<<<STAT_BLOCKS + degBlocks, 256, 0, stream>>>(x, N, partials, STAT_BLOCKS,
                                                           dstp, E, cnt);
    mid_combo<<<offsBlocks + 16, 256, 0, stream>>>(cnt, N, start, wcur, counter, dinv,
                                                   partials, STAT_BLOCKS, offsBlocks,
                                                   W1, W2, WT1, WT2, bias0);

    // ---- layer 1 GEMM + edge bucketing overlapped in one dispatch
    gemm1_fill<<<gemmGrid + degBlocks, 256, 0, stream>>>(x, WT1, bias0, bufA, N, gemmGrid,
                                                         srcp, dstp, dinv, wcur, edata, E);
    aggregate<false><<<aggGrid, 256, 0, stream>>>(bufA, dinv, start, cnt, edata, b1,
                                                  bufB, nullptr, nullptr, nullptr,
                                                  nullptr, N);

    // ---- layer 2 + pool fused (h2 never materialized; atomic-free partials)
    gemm_mfma2<<<gemmGrid, 256, 0, stream>>>(bufB, WT2, bufA, N);
    aggregate<true><<<aggGrid, 256, 0, stream>>>(bufA, dinv, start, cnt, edata, b2,
                                                 nullptr, batch, pool_part, ptag,
                                                 (float*)d_out, N);
    pool_reduce<<<256, 128, 0, stream>>>(pool_part, ptag, aggGrid, (float*)d_out);
}

// Round 10
// 404.239 us; speedup vs baseline: 1.4444x; 1.0011x over previous
//
#include <hip/hip_runtime.h>

#define FDIM 128  // feature dim == hidden dim

typedef __attribute__((ext_vector_type(8))) short short8;   // 8 bf16 (4 VGPRs)
typedef __attribute__((ext_vector_type(4))) float f32x4;    // MFMA accumulator

__device__ inline unsigned short f2bf(float f) {  // round-to-nearest-even
    unsigned int u = __float_as_uint(f);
    unsigned int r = u + 0x7FFFu + ((u >> 16) & 1u);
    return (unsigned short)(r >> 16);
}
__device__ inline float bf2f(unsigned short b) {
    return __uint_as_float((unsigned int)b << 16);
}
__device__ inline void bf8_fma(short8 v, float c, float* acc) {
#pragma unroll
    for (int k = 0; k < 8; ++k)
        acc[k] = fmaf(bf2f(((const unsigned short*)&v)[k]), c, acc[k]);
}

// ---------------------------------------------------------------------------
// 1) heterogeneous pre-pass: blocks [0,statBlocks) = column sum/sumsq partials
//    (BW-bound sweep of x); blocks >= statBlocks = dst-degree atomics
//    (latency-bound) — merged so the two run concurrently.
__global__ __launch_bounds__(256) void pre_combo(const float* __restrict__ x, int N,
                                                 float* __restrict__ partials, int statBlocks,
                                                 const int* __restrict__ dst, int E,
                                                 int* __restrict__ cnt) {
    if ((int)blockIdx.x >= statBlocks) {
        int e = (blockIdx.x - statBlocks) * 256 + threadIdx.x;
        if (e < E) atomicAdd(&cnt[dst[e]], 1);
        return;
    }
    const int c4 = threadIdx.x & 31;
    const int rg = threadIdx.x >> 5;
    float4 s = make_float4(0.f, 0.f, 0.f, 0.f);
    float4 q = make_float4(0.f, 0.f, 0.f, 0.f);
    for (long r = (long)blockIdx.x * 8 + rg; r < N; r += (long)statBlocks * 8) {
        float4 v = ((const float4*)x)[r * 32 + c4];
        s.x += v.x; s.y += v.y; s.z += v.z; s.w += v.w;
        q.x += v.x * v.x; q.y += v.y * v.y; q.z += v.z * v.z; q.w += v.w * v.w;
    }
    __shared__ float red[8][32][8];
    float* p = red[rg][c4];
    p[0] = s.x; p[1] = s.y; p[2] = s.z; p[3] = s.w;
    p[4] = q.x; p[5] = q.y; p[6] = q.z; p[7] = q.w;
    __syncthreads();
    if (rg == 0) {
#pragma unroll
        for (int g = 1; g < 8; ++g) {
            const float* o = red[g][c4];
#pragma unroll
            for (int j = 0; j < 8; ++j) red[0][c4][j] += o[j];
        }
        const float* r0 = red[0][c4];
        float* out = &partials[(size_t)blockIdx.x * 256];
        ((float4*)out)[c4] = make_float4(r0[0], r0[1], r0[2], r0[3]);
        ((float4*)(out + 128))[c4] = make_float4(r0[4], r0[5], r0[6], r0[7]);
    }
}

// ---------------------------------------------------------------------------
// 2) mid_combo: blocks [0, offsBlocks) = per-node edge-range scan + dinv;
//    blocks offsBlocks..+8 = W1 stats-slice reduce + scaled transpose + bias0;
//    blocks +8..+16 = W2 transpose.
__global__ __launch_bounds__(256) void mid_combo(const int* __restrict__ cnt, int N,
                                                 int* __restrict__ start,
                                                 int* __restrict__ wcur,
                                                 int* __restrict__ counter,
                                                 float* __restrict__ dinv,
                                                 const float* __restrict__ partials,
                                                 int nblk, int offsBlocks,
                                                 const float* __restrict__ W1,
                                                 const float* __restrict__ W2,
                                                 unsigned short* __restrict__ WT1,
                                                 unsigned short* __restrict__ WT2,
                                                 float* __restrict__ bias0) {
    const int tid = threadIdx.x;
    if ((int)blockIdx.x < offsBlocks) {
        __shared__ int sh[256];
        __shared__ int base;
        int i = blockIdx.x * 256 + tid;
        int v = (i < N) ? cnt[i] : 0;
        sh[tid] = v;
        __syncthreads();
        for (int off = 1; off < 256; off <<= 1) {
            int t = (tid >= off) ? sh[tid - off] : 0;
            __syncthreads();
            sh[tid] += t;
            __syncthreads();
        }
        if (tid == 255) base = atomicAdd(counter, sh[255]);
        __syncthreads();
        int excl = base + sh[tid] - v;
        if (i < N) {
            start[i] = excl;
            wcur[i] = excl;
            dinv[i] = rsqrtf((float)v + 1.0f);
        }
        return;
    }
    const int b = blockIdx.x - offsBlocks;  // 0..15
    const int h = tid & 127;
    const int seg = tid >> 7;  // 0,1
    if (b < 8) {
        // reduce this block's 32-col slice: 16 sum cols + 16 sumsq cols
        __shared__ float red[32][32];  // [rowgroup][localcol] 4 KB
        __shared__ float scol[32], mean_sh[16], rstd_sh[16];
        const int rg = tid >> 3;      // 0..31
        const int f = tid & 7;        // 0..7
        const int colbase = (f < 4) ? (b * 16 + f * 4) : (128 + b * 16 + (f - 4) * 4);
        float4 a = make_float4(0.f, 0.f, 0.f, 0.f);
        for (int row = rg; row < nblk; row += 32) {
            float4 v = *(const float4*)&partials[(size_t)row * 256 + colbase];
            a.x += v.x; a.y += v.y; a.z += v.z; a.w += v.w;
        }
        *(float4*)&red[rg][f * 4] = a;
        __syncthreads();
        if (tid < 32) {
            float s = 0.f;
#pragma unroll
            for (int r = 0; r < 32; ++r) s += red[r][tid];
            scol[tid] = s;
        }
        __syncthreads();
        if (tid < 16) {
            float m = scol[tid] / (float)N;
            float var = (scol[16 + tid] - (float)N * m * m) / (float)(N - 1);
            mean_sh[tid] = m;
            rstd_sh[tid] = rsqrtf(var);
        }
        __syncthreads();
        float acc = 0.f;
#pragma unroll
        for (int jj = 0; jj < 8; ++jj) {
            int jl = seg * 8 + jj;
            int j2 = b * 16 + jl;
            float w = W1[j2 * FDIM + h] * rstd_sh[jl];
            WT1[h * FDIM + j2] = f2bf(w);
            acc += mean_sh[jl] * w;
        }
        unsafeAtomicAdd(&bias0[h], -acc);
    } else {
#pragma unroll
        for (int jj = 0; jj < 8; ++jj) {
            int j2 = (b - 8) * 16 + seg * 8 + jj;
            WT2[h * FDIM + j2] = f2bf(W2[j2 * FDIM + h]);
        }
    }
}

// ---------------------------------------------------------------------------
// 3) GEMM1 + edge-bucketing merged. MFMA operands SWAPPED (W-frag as A,
//    x-frag as B) so D comes out transposed: m=h-within-tile (quad*4+reg),
//    n=x-row (lane&15). Epilogue = 8 contiguous short4 stores per lane
//    (round 9's layout needed 32 scalar 2B stores -> 38 MB write amplification).
__global__ __launch_bounds__(256) void gemm1_fill(const float* __restrict__ A,
                                                  const unsigned short* __restrict__ WT,
                                                  const float* __restrict__ bias,
                                                  unsigned short* __restrict__ C, int M,
                                                  int gemmBlocks,
                                                  const int* __restrict__ src,
                                                  const int* __restrict__ dst,
                                                  const float* __restrict__ dinv,
                                                  int* __restrict__ wcur,
                                                  int2* __restrict__ edata, int E) {
    const int tid = threadIdx.x;
    if ((int)blockIdx.x >= gemmBlocks) {
        int e = (blockIdx.x - gemmBlocks) * 256 + tid;
        if (e < E) {
            int s = src[e], d = dst[e];
            int pos = atomicAdd(&wcur[d], 1);
            edata[pos] = make_int2(s, __float_as_int(dinv[s] * dinv[d]));
        }
        return;
    }
    constexpr int LDA = 136;
    __shared__ unsigned short Alds[64 * LDA];
    __shared__ unsigned short Wlds[FDIM * LDA];
    const int row0 = blockIdx.x * 64;

    for (int i = tid; i < FDIM * 16; i += 256) {
        int r = i >> 4, g = i & 15;
        *(int4*)&Wlds[r * LDA + g * 8] = *(const int4*)&WT[r * FDIM + g * 8];
    }
    for (int i = tid; i < 64 * 32; i += 256) {
        int r = i >> 5, c4 = i & 31;
        int row = row0 + r;
        float4 v = make_float4(0.f, 0.f, 0.f, 0.f);
        if (row < M) v = ((const float4*)A)[(size_t)row * 32 + c4];
        ushort4 p;
        p.x = f2bf(v.x); p.y = f2bf(v.y); p.z = f2bf(v.z); p.w = f2bf(v.w);
        *(ushort4*)&Alds[r * LDA + c4 * 4] = p;
    }
    __syncthreads();

    const int lane = tid & 63;
    const int wave = tid >> 6;
    const int m16 = lane & 15;
    const int quad = lane >> 4;

    f32x4 acc[8];
#pragma unroll
    for (int t = 0; t < 8; ++t) acc[t] = (f32x4){0.f, 0.f, 0.f, 0.f};

    const unsigned short* Abase = &Alds[(wave * 16 + m16) * LDA + quad * 8];
    const unsigned short* Wbase = &Wlds[m16 * LDA + quad * 8];
#pragma unroll
    for (int s = 0; s < 4; ++s) {
        short8 a = *(const short8*)&Abase[s * 32];
#pragma unroll
        for (int t = 0; t < 8; ++t) {
            short8 b = *(const short8*)&Wbase[t * 16 * LDA + s * 32];
            // swapped: W-frag is the A operand -> D[m=h][n=x-row]
            acc[t] = __builtin_amdgcn_mfma_f32_16x16x32_bf16(b, a, acc[t], 0, 0, 0);
        }
    }

    // epilogue: lane's x-row = m16 (fixed); per t a contiguous short4 at
    // col t*16 + quad*4.
    const int r = row0 + wave * 16 + m16;
    if (r < M) {
#pragma unroll
        for (int t = 0; t < 8; ++t) {
            ushort4 o;
            o.x = f2bf(acc[t][0] + bias[t * 16 + quad * 4 + 0]);
            o.y = f2bf(acc[t][1] + bias[t * 16 + quad * 4 + 1]);
            o.z = f2bf(acc[t][2] + bias[t * 16 + quad * 4 + 2]);
            o.w = f2bf(acc[t][3] + bias[t * 16 + quad * 4 + 3]);
            *(ushort4*)&C[(size_t)r * FDIM + t * 16 + quad * 4] = o;
        }
    }
}

// ---------------------------------------------------------------------------
// 4) bf16 MFMA GEMM (layer 2: bf16 input, no bias), same swapped-operand form
__global__ __launch_bounds__(256) void gemm_mfma2(const unsigned short* __restrict__ A,
                                                  const unsigned short* __restrict__ WT,
                                                  unsigned short* __restrict__ C, int M) {
    constexpr int LDA = 136;
    __shared__ unsigned short Alds[64 * LDA];
    __shared__ unsigned short Wlds[FDIM * LDA];
    const int tid = threadIdx.x;
    const int row0 = blockIdx.x * 64;

    for (int i = tid; i < FDIM * 16; i += 256) {
        int r = i >> 4, g = i & 15;
        *(int4*)&Wlds[r * LDA + g * 8] = *(const int4*)&WT[r * FDIM + g * 8];
    }
    for (int i = tid; i < 64 * 16; i += 256) {
        int r = i >> 4, g = i & 15;
        int row = row0 + r;
        int4 v = make_int4(0, 0, 0, 0);
        if (row < M) v = *(const int4*)&A[(size_t)row * FDIM + g * 8];
        *(int4*)&Alds[r * LDA + g * 8] = v;
    }
    __syncthreads();

    const int lane = tid & 63;
    const int wave = tid >> 6;
    const int m16 = lane & 15;
    const int quad = lane >> 4;

    f32x4 acc[8];
#pragma unroll
    for (int t = 0; t < 8; ++t) acc[t] = (f32x4){0.f, 0.f, 0.f, 0.f};

    const unsigned short* Abase = &Alds[(wave * 16 + m16) * LDA + quad * 8];
    const unsigned short* Wbase = &Wlds[m16 * LDA + quad * 8];
#pragma unroll
    for (int s = 0; s < 4; ++s) {
        short8 a = *(const short8*)&Abase[s * 32];
#pragma unroll
        for (int t = 0; t < 8; ++t) {
            short8 b = *(const short8*)&Wbase[t * 16 * LDA + s * 32];
            acc[t] = __builtin_amdgcn_mfma_f32_16x16x32_bf16(b, a, acc[t], 0, 0, 0);
        }
    }

    const int r = row0 + wave * 16 + m16;
    if (r < M) {
#pragma unroll
        for (int t = 0; t < 8; ++t) {
            ushort4 o;
            o.x = f2bf(acc[t][0]); o.y = f2bf(acc[t][1]);
            o.z = f2bf(acc[t][2]); o.w = f2bf(acc[t][3]);
            *(ushort4*)&C[(size_t)r * FDIM + t * 16 + quad * 4] = o;
        }
    }
}

// ---------------------------------------------------------------------------
// 5) aggregation (bf16 in, fp32 accum, relu). 16 lanes/node, 16 nodes/block,
//    4x-unrolled edge loop. POOL=false: store bf16 rows. POOL=true: per-block
//    pool partial via plain LDS writes + tree reduce + one coalesced 512B
//    store (tag g0); boundary blocks (~63/12500) use direct atomics (tag -1).
template <bool POOL>
__global__ __launch_bounds__(256) void aggregate(const unsigned short* __restrict__ xw,
                                                 const float* __restrict__ dinv,
                                                 const int* __restrict__ start,
                                                 const int* __restrict__ cnt,
                                                 const int2* __restrict__ edata,
                                                 const float* __restrict__ bvec,
                                                 unsigned short* __restrict__ out,
                                                 const int* __restrict__ batch,
                                                 float* __restrict__ pool_part,
                                                 int* __restrict__ ptag,
                                                 float* __restrict__ pooled, int N) {
    const int base = blockIdx.x * 16;
    const int node = base + (threadIdx.x >> 4);
    const int l8 = threadIdx.x & 15;  // 8-col group
    const bool active = node < N;
    if (!POOL && !active) return;
    const int nidx = active ? node : (N - 1);

    float dv = dinv[nidx];
    float d2 = dv * dv;
    float4 b0 = ((const float4*)bvec)[l8 * 2];
    float4 b1 = ((const float4*)bvec)[l8 * 2 + 1];
    float acc[8] = {b0.x, b0.y, b0.z, b0.w, b1.x, b1.y, b1.z, b1.w};
    short8 sv = *(const short8*)&xw[(size_t)nidx * FDIM + l8 * 8];
    bf8_fma(sv, d2, acc);

    int j = start[nidx];
    const int s1 = j + (active ? cnt[nidx] : 0);
    for (; j + 4 <= s1; j += 4) {
        int2 e0 = edata[j], e1 = edata[j + 1], e2 = edata[j + 2], e3 = edata[j + 3];
        short8 u0 = *(const short8*)&xw[(size_t)e0.x * FDIM + l8 * 8];
        short8 u1 = *(const short8*)&xw[(size_t)e1.x * FDIM + l8 * 8];
        short8 u2 = *(const short8*)&xw[(size_t)e2.x * FDIM + l8 * 8];
        short8 u3 = *(const short8*)&xw[(size_t)e3.x * FDIM + l8 * 8];
        bf8_fma(u0, __int_as_float(e0.y), acc);
        bf8_fma(u1, __int_as_float(e1.y), acc);
        bf8_fma(u2, __int_as_float(e2.y), acc);
        bf8_fma(u3, __int_as_float(e3.y), acc);
    }
    for (; j < s1; ++j) {
        int2 ed = edata[j];
        short8 u = *(const short8*)&xw[(size_t)ed.x * FDIM + l8 * 8];
        bf8_fma(u, __int_as_float(ed.y), acc);
    }

    if constexpr (!POOL) {
        short8 o;
#pragma unroll
        for (int k = 0; k < 8; ++k)
            ((unsigned short*)&o)[k] = f2bf(fmaxf(acc[k], 0.f));
        *(short8*)&out[(size_t)node * FDIM + l8 * 8] = o;
    } else {
        float r[8];
#pragma unroll
        for (int k = 0; k < 8; ++k) r[k] = active ? fmaxf(acc[k], 0.f) : 0.f;
        int g0 = batch[base];
        int g1 = batch[min(base + 15, N - 1)];
        if (g0 == g1) {  // block-uniform branch — safe around __syncthreads
            __shared__ float red[16][FDIM];  // 8 KB; plain writes, no LDS atomics
            float* dst = &red[threadIdx.x >> 4][l8 * 8];
            *(float4*)dst = make_float4(r[0], r[1], r[2], r[3]);
            *(float4*)(dst + 4) = make_float4(r[4], r[5], r[6], r[7]);
            __syncthreads();
            if (threadIdx.x < FDIM) {
                float s = 0.f;
#pragma unroll
                for (int i = 0; i < 16; ++i) s += red[i][threadIdx.x];
                pool_part[(size_t)blockIdx.x * FDIM + threadIdx.x] = s;
                if (threadIdx.x == 0) ptag[blockIdx.x] = g0;
            }
        } else {  // rare boundary block: direct atomics, slot skipped
            if (threadIdx.x == 0) ptag[blockIdx.x] = -1;
            if (active) {
                int g = batch[node];
#pragma unroll
                for (int k = 0; k < 8; ++k)
                    unsafeAtomicAdd(&pooled[g * FDIM + l8 * 8 + k], r[k]);
            }
        }
    }
}

// ---------------------------------------------------------------------------
// 6) reduce tagged per-block pool partials into d_out (tags monotone).
__global__ __launch_bounds__(128) void pool_reduce(const float* __restrict__ pool_part,
                                                   const int* __restrict__ ptag,
                                                   int nslots, float* __restrict__ out) {
    int per = (nslots + gridDim.x - 1) / gridDim.x;
    int s0 = blockIdx.x * per;
    int s1 = min(s0 + per, nslots);
    int t = threadIdx.x;
    float acc = 0.f;
    int cur = -1;
    for (int s = s0; s < s1; ++s) {
        int g = ptag[s];  // broadcast scalar load
        if (g < 0) continue;
        if (g != cur) {
            if (cur >= 0) unsafeAtomicAdd(&out[cur * FDIM + t], acc);
            acc = 0.f;
            cur = g;
        }
        acc += pool_part[(size_t)s * FDIM + t];
    }
    if (cur >= 0) unsafeAtomicAdd(&out[cur * FDIM + t], acc);
}

// ---------------------------------------------------------------------------
extern "C" void kernel_launch(void* const* d_in, const int* in_sizes, int n_in,
                              void* d_out, int out_size, void* d_ws, size_t ws_size,
                              hipStream_t stream) {
    const float* x = (const float*)d_in[0];
    const int* ei = (const int*)d_in[1];
    const int* batch = (const int*)d_in[2];
    const float* W1 = (const float*)d_in[4];
    const float* b1 = (const float*)d_in[5];
    const float* W2 = (const float*)d_in[6];
    const float* b2 = (const float*)d_in[7];

    const int N = in_sizes[2];
    const int E = in_sizes[1] / 2;
    const int* srcp = ei;
    const int* dstp = ei + E;

    const size_t NF = (size_t)N * FDIM;
    const int aggGrid = (N + 15) / 16;
    unsigned short* bufA = (unsigned short*)d_ws;  // N*128 bf16 (xw)
    unsigned short* bufB = bufA + NF;              // N*128 bf16 (h1)
    int* cnt = (int*)(bufB + NF);                  // N      <- memset from here
    int* counter = cnt + N;                        // 4
    float* bias0 = (float*)(counter + 4);          // 128    <- memset to here
    float* dinv = bias0 + FDIM;                    // N
    int* start = (int*)(dinv + N);                 // N
    int* wcur = start + N;                         // N
    unsigned short* WT1 = (unsigned short*)(wcur + N);  // 128*128 bf16
    unsigned short* WT2 = WT1 + FDIM * FDIM;            // 128*128 bf16
    int2* edata = (int2*)(WT2 + FDIM * FDIM);      // E x {src, coef}
    float* pool_part = (float*)(edata + E);        // aggGrid*128 f32
    int* ptag = (int*)(pool_part + (size_t)aggGrid * FDIM);  // aggGrid
    float* partials = (float*)edata;               // aliased; dead before gemm1_fill
    const int STAT_BLOCKS = 512;

    hipMemsetAsync(cnt, 0, ((size_t)N + 4 + FDIM) * sizeof(int), stream);
    hipMemsetAsync(d_out, 0, (size_t)out_size * sizeof(float), stream);

    const int degBlocks = (E + 255) / 256;
    const int offsBlocks = (N + 255) / 256;
    const int gemmGrid = (N + 63) / 64;

    pre_combo<<<STAT_BLOCKS + degBlocks, 256, 0, stream>>>(x, N, partials, STAT_BLOCKS,
                                                           dstp, E, cnt);
    mid_combo<<<offsBlocks + 16, 256, 0, stream>>>(cnt, N, start, wcur, counter, dinv,
                                                   partials, STAT_BLOCKS, offsBlocks,
                                                   W1, W2, WT1, WT2, bias0);

    // ---- layer 1 GEMM + edge bucketing overlapped in one dispatch
    gemm1_fill<<<gemmGrid + degBlocks, 256, 0, stream>>>(x, WT1, bias0, bufA, N, gemmGrid,
                                                         srcp, dstp, dinv, wcur, edata, E);
    aggregate<false><<<aggGrid, 256, 0, stream>>>(bufA, dinv, start, cnt, edata, b1,
                                                  bufB, nullptr, nullptr, nullptr,
                                                  nullptr, N);

    // ---- layer 2 + pool fused (h2 never materialized; atomic-free partials)
    gemm_mfma2<<<gemmGrid, 256, 0, stream>>>(bufB, WT2, bufA, N);
    aggregate<true><<<aggGrid, 256, 0, stream>>>(bufA, dinv, start, cnt, edata, b2,
                                                 nullptr, batch, pool_part, ptag,
                                                 (float*)d_out, N);
    pool_reduce<<<256, 128, 0, stream>>>(pool_part, ptag, aggGrid, (float*)d_out);
}